// Round 1
// baseline (14561.090 us; speedup 1.0000x reference)
//
#include <hip/hip_runtime.h>

typedef short bf16x8 __attribute__((ext_vector_type(8)));
typedef float f32x4 __attribute__((ext_vector_type(4)));

static constexpr int kT  = 256;
static constexpr int kNU = 64;
static constexpr int kNX = 128;
static constexpr int kNY = 16;
static constexpr int kBT = 16;   // batch rows per block

// packed weight region sizes (elements)
static constexpr int kW1P = 64 * 6 * 64 * 8;   // 196608
static constexpr int kW2P = 8 * 32 * 64 * 8;   // 131072
static constexpr int kCP  = 4 * 64 * 8;        // 2048
static constexpr int kDP  = 2 * 64 * 8;        // 1024
static constexpr int kPackTotal = kW1P + kW2P + kCP + kDP; // 330752

__device__ __forceinline__ unsigned short f2bf(float f) {
  union { float f; unsigned int u; } v; v.f = f;
  unsigned int r = v.u + 0x7fffu + ((v.u >> 16) & 1u);   // RNE to bf16
  return (unsigned short)(r >> 16);
}

// Pack W1/W2/C/D (fp32) into bf16 MFMA B-fragment order:
// frag index (n, ks, lane, j) holds W[16n + (lane&15)][32ks + 8*(lane>>4) + j]
__global__ __launch_bounds__(256)
void prepack_kernel(const float* __restrict__ W1, const float* __restrict__ W2,
                    const float* __restrict__ C, const float* __restrict__ D,
                    unsigned short* __restrict__ wp) {
  int i = blockIdx.x * 256 + threadIdx.x;
  if (i >= kPackTotal) return;
  float v;
  if (i < kW1P) {
    int j = i & 7, l = (i >> 3) & 63, t = i >> 9;
    int ks = t % 6, n = t / 6;
    v = W1[(16 * n + (l & 15)) * 192 + 32 * ks + 8 * (l >> 4) + j];
  } else if (i < kW1P + kW2P) {
    int k = i - kW1P;
    int j = k & 7, l = (k >> 3) & 63, t = k >> 9;
    int ks = t & 31, n = t >> 5;
    v = W2[(16 * n + (l & 15)) * 1024 + 32 * ks + 8 * (l >> 4) + j];
  } else if (i < kW1P + kW2P + kCP) {
    int k = i - (kW1P + kW2P);
    int j = k & 7, l = (k >> 3) & 63, ks = k >> 9;
    v = C[(l & 15) * 128 + 32 * ks + 8 * (l >> 4) + j];
  } else {
    int k = i - (kW1P + kW2P + kCP);
    int j = k & 7, l = (k >> 3) & 63, ks = k >> 9;
    v = D[(l & 15) * 64 + 32 * ks + 8 * (l >> 4) + j];
  }
  wp[i] = f2bf(v);
}

// RK45 stage-combination coefficients (dt folded in), row e = coeffs for z of stage e+2
__constant__ float CTc[5][5] = {
  {(float)(0.01 / 4.0), 0.f, 0.f, 0.f, 0.f},
  {(float)(0.01 * 3.0 / 32.0), (float)(0.01 * 9.0 / 32.0), 0.f, 0.f, 0.f},
  {(float)(0.01 * 1932.0 / 2197.0), (float)(-0.01 * 7200.0 / 2197.0), (float)(0.01 * 7296.0 / 2197.0), 0.f, 0.f},
  {(float)(0.01 * 439.0 / 216.0), (float)(-0.01 * 8.0), (float)(0.01 * 3680.0 / 513.0), (float)(-0.01 * 845.0 / 4104.0), 0.f},
  {(float)(-0.01 * 8.0 / 27.0), (float)(0.01 * 2.0), (float)(-0.01 * 3544.0 / 2565.0), (float)(0.01 * 1859.0 / 4104.0), (float)(-0.01 * 11.0 / 40.0)}
};

__device__ __forceinline__ float tanh_fast(float x) {
  float p = x * 2.8853900817779268f;          // 2*log2(e)
  p = fminf(fmaxf(p, -80.f), 80.f);
  float t = exp2f(p);
  return (t - 1.f) / (t + 1.f);
}

// One block = 16 batch rows, 8 waves. Whole T-loop runs inside the kernel.
__global__ __launch_bounds__(512, 2)
void rk45_kernel(const float* __restrict__ u, const float* __restrict__ x0,
                 const float* __restrict__ b1g, const float* __restrict__ b2g,
                 const unsigned short* __restrict__ wp,
                 float* __restrict__ Xout, float* __restrict__ Yout) {
  // strides chosen 16B-aligned with odd-ish dword phase to limit bank conflicts
  __shared__ unsigned short zs[16][232];   // z = [x | u] bf16 (cols 0..127 x, 128..191 u)
  __shared__ unsigned short hs[16][1048];  // h bf16 (16 x 1024)
  __shared__ float xs[16][132];            // master state fp32
  __shared__ float b1s[1024];

  const int tid  = threadIdx.x;
  const int lane = tid & 63;
  const int w    = tid >> 6;     // wave 0..7
  const int r16  = lane & 15;
  const int g    = lane >> 4;    // 0..3
  const int b0   = blockIdx.x * kBT;
  const int colw = 16 * w + r16; // this lane's NX column in matmul2 mapping

  const bf16x8* W1P = (const bf16x8*)wp;
  const bf16x8* W2P = (const bf16x8*)(wp + kW1P);
  const bf16x8* CP  = (const bf16x8*)(wp + kW1P + kW2P);
  const bf16x8* DP  = (const bf16x8*)(wp + kW1P + kW2P + kCP);

  float xreg[4];
  f32x4 k1r = {0,0,0,0}, k2r = {0,0,0,0}, k3r = {0,0,0,0}, k4r = {0,0,0,0}, k5r = {0,0,0,0};
  const float b2reg = b2g[colw];

  b1s[tid] = b1g[tid];
  b1s[tid + 512] = b1g[tid + 512];

  #pragma unroll
  for (int q = 0; q < 4; ++q) {
    int row = 4 * g + q;
    float xv = x0[(b0 + row) * kNX + colw];
    xreg[q] = xv;
    xs[row][colw] = xv;
    zs[row][colw] = f2bf(xv);
  }
  __syncthreads();

  const float D1 = (float)(0.01 * 16.0 / 135.0);
  const float D3 = (float)(0.01 * 6656.0 / 12825.0);
  const float D4 = (float)(0.01 * 28561.0 / 56430.0);
  const float D5 = (float)(-0.01 * 9.0 / 50.0);
  const float D6 = (float)(0.01 * 2.0 / 55.0);

  #pragma unroll 1
  for (int t = 0; t < kT; ++t) {
    // ---- stage A: write X[t] = x_t, load u_t into zs u-part
    {
      int base = tid * 4, row = base >> 7, col = base & 127;
      float4 xv = *(const float4*)&xs[row][col];
      *(float4*)&Xout[((b0 + row) * kT + t) * kNX + col] = xv;
      int urow = tid >> 5, ucol = (tid & 31) * 2;
      float2 uv = *(const float2*)&u[((b0 + urow) * kT + t) * kNU + ucol];
      zs[urow][kNX + ucol]     = f2bf(uv.x);
      zs[urow][kNX + ucol + 1] = f2bf(uv.y);
    }
    __syncthreads();

    #pragma unroll 1
    for (int e = 0; e < 6; ++e) {
      // ---- matmul1: h = tanh(z @ W1^T + b1); wave w owns NH slice [128w, 128w+128)
      bf16x8 za[6];
      #pragma unroll
      for (int ks = 0; ks < 6; ++ks)
        za[ks] = *(const bf16x8*)&zs[r16][8 * g + 32 * ks];

      #pragma unroll 2
      for (int nt = 0; nt < 8; ++nt) {
        int n = 8 * w + nt;
        const bf16x8* w1p = W1P + n * 6 * 64 + lane;
        f32x4 aa = {0,0,0,0}, ab = {0,0,0,0};
        #pragma unroll
        for (int ks = 0; ks < 6; ks += 2) {
          aa = __builtin_amdgcn_mfma_f32_16x16x32_bf16(za[ks],     w1p[ks * 64],       aa, 0, 0, 0);
          ab = __builtin_amdgcn_mfma_f32_16x16x32_bf16(za[ks + 1], w1p[(ks + 1) * 64], ab, 0, 0, 0);
        }
        float bias = b1s[16 * n + r16];
        #pragma unroll
        for (int q = 0; q < 4; ++q) {
          float hv = tanh_fast(aa[q] + ab[q] + bias);
          hs[4 * g + q][16 * n + r16] = f2bf(hv);
        }
      }
      if (e == 0 && w == 0) {
        // y_t = x C^T + u D^T, reuses z fragments (z k 0..127 = x -> C, 128..191 = u -> D)
        f32x4 ay = {0,0,0,0};
        #pragma unroll
        for (int ks = 0; ks < 4; ++ks)
          ay = __builtin_amdgcn_mfma_f32_16x16x32_bf16(za[ks], CP[ks * 64 + lane], ay, 0, 0, 0);
        ay = __builtin_amdgcn_mfma_f32_16x16x32_bf16(za[4], DP[lane],      ay, 0, 0, 0);
        ay = __builtin_amdgcn_mfma_f32_16x16x32_bf16(za[5], DP[64 + lane], ay, 0, 0, 0);
        #pragma unroll
        for (int q = 0; q < 4; ++q)
          Yout[((b0 + 4 * g + q) * kT + t) * kNY + r16] = ay[q];
      }
      __syncthreads();

      // ---- matmul2: k = h @ W2^T + b2; wave w owns NX cols [16w, 16w+16)
      f32x4 ka = {0,0,0,0}, kb = {0,0,0,0};
      const bf16x8* w2p = W2P + w * 32 * 64 + lane;
      #pragma unroll 8
      for (int ks = 0; ks < 32; ks += 2) {
        bf16x8 h0 = *(const bf16x8*)&hs[r16][8 * g + 32 * ks];
        bf16x8 h1 = *(const bf16x8*)&hs[r16][8 * g + 32 * (ks + 1)];
        ka = __builtin_amdgcn_mfma_f32_16x16x32_bf16(h0, w2p[ks * 64],       ka, 0, 0, 0);
        kb = __builtin_amdgcn_mfma_f32_16x16x32_bf16(h1, w2p[(ks + 1) * 64], kb, 0, 0, 0);
      }
      f32x4 kv = ka + kb;
      #pragma unroll
      for (int q = 0; q < 4; ++q) kv[q] += b2reg;

      if      (e == 0) k1r = kv;
      else if (e == 1) k2r = kv;
      else if (e == 2) k3r = kv;
      else if (e == 3) k4r = kv;
      else if (e == 4) k5r = kv;

      if (e < 5) {
        // z for next stage: x + sum(CT[e][j] * k_j)  (unused k's are 0-coef, stale-but-finite)
        float c1 = CTc[e][0], c2 = CTc[e][1], c3 = CTc[e][2], c4 = CTc[e][3], c5 = CTc[e][4];
        #pragma unroll
        for (int q = 0; q < 4; ++q) {
          float xt = xreg[q] + c1 * k1r[q] + c2 * k2r[q] + c3 * k3r[q] + c4 * k4r[q] + c5 * k5r[q];
          zs[4 * g + q][colw] = f2bf(xt);
        }
      } else {
        // x_{t+1} = x_t + dt * (16/135 k1 + 6656/12825 k3 + 28561/56430 k4 - 9/50 k5 + 2/55 k6)
        #pragma unroll
        for (int q = 0; q < 4; ++q) {
          float xn = xreg[q] + (D1 * k1r[q] + D3 * k3r[q] + D4 * k4r[q] + D5 * k5r[q] + D6 * kv[q]);
          xreg[q] = xn;
          xs[4 * g + q][colw] = xn;
          zs[4 * g + q][colw] = f2bf(xn);
        }
      }
      __syncthreads();
    }
  }
}

extern "C" void kernel_launch(void* const* d_in, const int* in_sizes, int n_in,
                              void* d_out, int out_size, void* d_ws, size_t ws_size,
                              hipStream_t stream) {
  const float* u  = (const float*)d_in[0];
  const float* x0 = (const float*)d_in[1];
  const float* W1 = (const float*)d_in[2];
  const float* b1 = (const float*)d_in[3];
  const float* W2 = (const float*)d_in[4];
  const float* b2 = (const float*)d_in[5];
  const float* C  = (const float*)d_in[6];
  const float* D  = (const float*)d_in[7];

  unsigned short* wp = (unsigned short*)d_ws;
  float* Xout = (float*)d_out;
  float* Yout = Xout + (size_t)512 * 256 * 128;

  hipLaunchKernelGGL(prepack_kernel, dim3(kPackTotal / 256), dim3(256), 0, stream,
                     W1, W2, C, D, wp);
  hipLaunchKernelGGL(rk45_kernel, dim3(32), dim3(512), 0, stream,
                     u, x0, b1, b2, (const unsigned short*)wp, Xout, Yout);
}